// Round 5
// baseline (1341.550 us; speedup 1.0000x reference)
//
#include <hip/hip_runtime.h>

typedef unsigned short u16t;
typedef __attribute__((ext_vector_type(8))) short short8;
typedef __attribute__((ext_vector_type(4))) short short4v;
typedef __attribute__((ext_vector_type(4))) float f32x4;
typedef __attribute__((ext_vector_type(2))) float f32x2;
typedef __attribute__((ext_vector_type(4))) unsigned short u16x4;
typedef __attribute__((ext_vector_type(4))) unsigned int u32x4;
typedef __attribute__((ext_vector_type(2))) unsigned int u32x2;
typedef __attribute__((ext_vector_type(4))) int i32x4;

__device__ __forceinline__ float bf2f(short b) {
  return __uint_as_float(((unsigned)(unsigned short)b) << 16);
}
__device__ __forceinline__ u16t f2bf(float f) {
  unsigned u = __float_as_uint(f);
  u += 0x7FFFu + ((u >> 16) & 1u);  // RNE
  return (u16t)(u >> 16);
}

// jax threefry2x32, key = (0, 42)
__device__ __forceinline__ bool keep_mask(unsigned flat) {
  const unsigned k0 = 0u, k1 = 42u;
  const unsigned k2 = k0 ^ k1 ^ 0x1BD11BDAu;
  unsigned x0 = 0u + k0;
  unsigned x1 = flat + k1;
#define TF_R(r) { x0 += x1; x1 = (x1 << r) | (x1 >> (32 - r)); x1 ^= x0; }
  TF_R(13) TF_R(15) TF_R(26) TF_R(6)  x0 += k1; x1 += k2 + 1u;
  TF_R(17) TF_R(29) TF_R(16) TF_R(24) x0 += k2; x1 += k0 + 2u;
  TF_R(13) TF_R(15) TF_R(26) TF_R(6)  x0 += k0; x1 += k1 + 3u;
  TF_R(17) TF_R(29) TF_R(16) TF_R(24) x0 += k1; x1 += k2 + 4u;
  TF_R(13) TF_R(15) TF_R(26) TF_R(6)  x0 += k2; x1 += k0 + 5u;
#undef TF_R
  return ((x0 ^ x1) >> 31) == 0u;
}

__device__ __forceinline__ void load_lds16(const u16t* g, u16t* l) {
  __builtin_amdgcn_global_load_lds((__attribute__((address_space(1))) void*)g,
                                   (__attribute__((address_space(3))) void*)l,
                                   16, 0, 0);
}

// ---- f32 -> bf16 conversion ----
__global__ void cvt_bf16(const float* __restrict__ s, u16t* __restrict__ d, int n) {
  int i = (blockIdx.x * 256 + threadIdx.x) * 4;
  if (i < n) {
    f32x4 v = *(const f32x4*)&s[i];
    u16x4 o = { f2bf(v.x), f2bf(v.y), f2bf(v.z), f2bf(v.w) };
    *(u16x4*)&d[i] = o;
  }
}

// ---- f32 -> bf16 for x, fused threefry mask precompute; mask is SLICE-MAJOR:
// mask[sl * Nn + node] so each slice-pass touches a 200KB contiguous region.
__global__ __launch_bounds__(256) void cvt_x_mask(const float* __restrict__ s,
    u16t* __restrict__ d, unsigned* __restrict__ mask, int n, int nn) {
  int t = blockIdx.x * 256 + threadIdx.x;
  int i = t * 4;
  if (i < n) {
    f32x4 v = *(const f32x4*)&s[i];
    u16x4 o = { f2bf(v.x), f2bf(v.y), f2bf(v.z), f2bf(v.w) };
    *(u16x4*)&d[i] = o;
  }
  if (t < nn * 16) {
    unsigned base = (unsigned)t * 32u;
    unsigned m = 0u;
    for (int k = 0; k < 32; ++k) m |= (keep_mask(base + (unsigned)k) ? 1u : 0u) << k;
    mask[(size_t)(t & 15) * nn + (t >> 4)] = m;
  }
}

// ---- CSR build ----
__global__ void count_edges(const int* __restrict__ dst, int E, int* __restrict__ cnt) {
  int e = blockIdx.x * 256 + threadIdx.x;
  if (e < E) atomicAdd(&cnt[dst[e]], 1);
}

// Degree-bin histogram: bucket = padded-chunk-count, clamped to 15.
__global__ void bin_hist(const int* __restrict__ cnt, int* __restrict__ hist, int n) {
  int i = blockIdx.x * 256 + threadIdx.x;
  if (i < n) {
    int b = (cnt[i] + 8) >> 3;  // chunks of padded (cnt+1 self) list
    atomicAdd(&hist[b < 15 ? b : 15], 1);
  }
}

__global__ void bin_scan(const int* __restrict__ hist, int* __restrict__ binCursor) {
  if (threadIdx.x == 0 && blockIdx.x == 0) {
    int s = 0;
    for (int b = 0; b < 16; ++b) { binCursor[b] = s; s += hist[b]; }
  }
}

// Padded CSR row build + degree-bin permutation. Each row: cnt edges, 1 self,
// padded to multiple of 8 with dummy index n (zero table row). perm groups
// nodes of equal chunk-count so waves run divergence-free gather loops.
__global__ __launch_bounds__(256) void rowp_build(const int* __restrict__ cnt,
    i32x4* __restrict__ ndr, int* __restrict__ cursor, float* __restrict__ dinv,
    int* __restrict__ gctr, u16t* __restrict__ colu,
    int* __restrict__ binCursor, u16t* __restrict__ perm, int n) {
  __shared__ int sd[256];
  __shared__ int sbase;
  const int tid = threadIdx.x;
  const int i = blockIdx.x * 256 + tid;
  int c = (i < n) ? cnt[i] : 0;
  int cs = c + 1;
  int p = (i < n) ? ((cs + 7) & ~7) : 0;
  int v = p;
  sd[tid] = v;
  __syncthreads();
  for (int o = 1; o < 256; o <<= 1) {
    int t2 = (tid >= o) ? sd[tid - o] : 0;
    __syncthreads();
    v += t2;
    sd[tid] = v;
    __syncthreads();
  }
  if (tid == 255) sbase = atomicAdd(gctr, v);
  __syncthreads();
  if (i < n) {
    int start = sbase + v - p;
    cursor[i] = start;
    float dv = rsqrtf((float)cs);
    dinv[i] = dv;
    i32x4 r;
    r[0] = start; r[1] = start + p; r[2] = __float_as_int(dv); r[3] = 0;
    ndr[i] = r;
    colu[start + c] = (u16t)i;                                  // self entry
    for (int q = c + 1; q < p; ++q) colu[start + q] = (u16t)n;  // dummies -> zero row
    int b = p >> 3;
    b = b < 15 ? b : 15;
    int slot = atomicAdd(&binCursor[b], 1);
    perm[slot] = (u16t)i;
  }
}

__global__ void fill_csr(const int* __restrict__ src, const int* __restrict__ dst, int E,
                         int* __restrict__ cursor, u16t* __restrict__ col) {
  int e = blockIdx.x * 256 + threadIdx.x;
  if (e < E) {
    int d = dst[e];
    int pos = atomicAdd(&cursor[d], 1);
    col[pos] = (u16t)src[e];
  }
}

// ---- bf16 GEMM, SLICE-MAJOR output, rows PRE-SCALED by dinv[row];
// rows >= Nclamp written as exact zeros (zero row for CSR dummies).
__global__ __launch_bounds__(256) void gemm_bt_sl(const u16t* __restrict__ A,
                                                  const u16t* __restrict__ B,
                                                  u16t* __restrict__ C,
                                                  int K, int Mrows,
                                                  const float* __restrict__ dinv,
                                                  int Nclamp) {
  __shared__ __align__(16) u16t lA[128 * 32];
  __shared__ __align__(16) u16t lB[128 * 32];
  const int tid = threadIdx.x;
  const int wave = tid >> 6, lane = tid & 63;
  const int wm = (wave & 1) * 64, wn = (wave >> 1) * 64;
  const int lrow = lane & 15, lq = lane >> 4;
  const u16t* Ab = A + (size_t)blockIdx.x * 128 * K;
  const u16t* Bb = B + (size_t)blockIdx.y * 128 * K;
  const int r0 = tid >> 2, c0 = (tid & 3) * 8;
  const int ldsOff = __builtin_amdgcn_readfirstlane((tid >> 6) * 512);

  f32x4 acc[4][4];
  const f32x4 zero = {0.f, 0.f, 0.f, 0.f};
#pragma unroll
  for (int mi = 0; mi < 4; ++mi)
#pragma unroll
    for (int ni = 0; ni < 4; ++ni) acc[mi][ni] = zero;

  for (int kt = 0; kt < K; kt += 32) {
    __syncthreads();
    load_lds16(Ab + (size_t)r0 * K + kt + c0, &lA[ldsOff]);
    load_lds16(Ab + (size_t)(r0 + 64) * K + kt + c0, &lA[2048 + ldsOff]);
    load_lds16(Bb + (size_t)r0 * K + kt + c0, &lB[ldsOff]);
    load_lds16(Bb + (size_t)(r0 + 64) * K + kt + c0, &lB[2048 + ldsOff]);
    __syncthreads();
    short8 af[4], bfr[4];
#pragma unroll
    for (int mi = 0; mi < 4; ++mi)
      af[mi] = *(const short8*)&lA[(wm + mi * 16 + lrow) * 32 + lq * 8];
#pragma unroll
    for (int ni = 0; ni < 4; ++ni)
      bfr[ni] = *(const short8*)&lB[(wn + ni * 16 + lrow) * 32 + lq * 8];
#pragma unroll
    for (int mi = 0; mi < 4; ++mi)
#pragma unroll
      for (int ni = 0; ni < 4; ++ni)
        acc[mi][ni] = __builtin_amdgcn_mfma_f32_16x16x32_bf16(af[mi], bfr[ni], acc[mi][ni], 0, 0, 0);
  }

  const int crow0 = blockIdx.x * 128 + wm + lq * 4;
  const int ccol0 = blockIdx.y * 128 + wn + lrow;
#pragma unroll
  for (int mi = 0; mi < 4; ++mi)
#pragma unroll
    for (int r = 0; r < 4; ++r) {
      const int row = crow0 + mi * 16 + r;
      const float dr = (row < Nclamp) ? dinv[row] : 0.f;
#pragma unroll
      for (int ni = 0; ni < 4; ++ni) {
        int cc = ccol0 + ni * 16;
        size_t idx = ((size_t)(cc >> 5) * Mrows + row) * 32 + (cc & 31);
        C[idx] = f2bf(dr * acc[mi][ni][r]);
      }
    }
}

// 8 edges: cols already in cw. Uniform SGPR base + 32-bit voffset (saddr-form
// global_load_dwordx2), shl/and bf16 unpack, f32x2 packed adds (v_pk_add_f32).
__device__ __forceinline__ void gather8(const char* __restrict__ Tb, u32x4 cw,
                                        unsigned flb, f32x2& a01, f32x2& a23) {
  unsigned off[8];
#pragma unroll
  for (int q = 0; q < 4; ++q) {
    off[2 * q]     = ((cw[q] & 0xFFFFu) << 6) | flb;
    off[2 * q + 1] = ((cw[q] >> 16) << 6) | flb;
  }
  u32x2 w[8];
#pragma unroll
  for (int q = 0; q < 8; ++q) w[q] = *(const u32x2*)(Tb + (size_t)off[q]);
#pragma unroll
  for (int q = 0; q < 8; ++q) {
    f32x2 v01 = { __uint_as_float(w[q].x << 16), __uint_as_float(w[q].x & 0xFFFF0000u) };
    f32x2 v23 = { __uint_as_float(w[q].y << 16), __uint_as_float(w[q].y & 0xFFFF0000u) };
    a01 += v01;
    a23 += v23;
  }
}

// ---- sliced propagate layer 1: 8 lanes/node, 32 nodes/block, degree-binned
// node order (perm) -> divergence-free chunk loops; padded CSR (no tails).
__global__ __launch_bounds__(256) void prop1_kernel(const u16t* __restrict__ T0,
    const u16t* __restrict__ colu, const i32x4* __restrict__ ndr,
    const u16t* __restrict__ perm, const float* __restrict__ b1,
    const unsigned* __restrict__ kmask,
    float* __restrict__ embf, u16t* __restrict__ embb, int n, int Mrows, int chunks) {
  const int t = threadIdx.x;
  const unsigned flb = (unsigned)(t & 7) * 8u;  // byte offset of lane's 4 feats
  const int fl4 = (t & 7) * 4;
  const int bid = blockIdx.x;
  const int half = chunks << 3;
  const int phase = bid >= half;
  const int rem = bid - (phase ? half : 0);
  const int sl = (rem & 7) + (phase << 3);
  const int slot = (rem >> 3) * 32 + (t >> 3);
  if (slot >= n) return;
  const int i = (int)perm[slot];

  const char* Tb = (const char*)T0 + (size_t)sl * ((size_t)Mrows * 64);
  const i32x4 nd = ndr[i];
  const float di = __int_as_float(nd[2]);
  f32x2 a01 = {0.f, 0.f}, a23 = {0.f, 0.f};

  int e = nd[0];
  const int end = nd[1];
  u32x4 cw = *(const u32x4*)&colu[e];
  e += 8;
  while (e < end) {
    u32x4 nw = *(const u32x4*)&colu[e];
    e += 8;
    gather8(Tb, cw, flb, a01, a23);
    cw = nw;
  }
  gather8(Tb, cw, flb, a01, a23);

  const int f = sl * 32 + fl4;
  const unsigned km = kmask[(size_t)sl * n + i];
  float acc[4] = {a01.x, a01.y, a23.x, a23.y};
  f32x4 o;
  short4v ob;
#pragma unroll
  for (int j = 0; j < 4; ++j) {
    float h = di * acc[j] + b1[f + j];
    h = fmaxf(h, 0.f);
    float eb = ((km >> (fl4 + j)) & 1u) ? 2.f * h : 0.f;
    o[j] = eb;
    ob[j] = (short)f2bf(eb);
  }
  __builtin_nontemporal_store(o, (f32x4*)&embf[(size_t)i * 512 + f]);
  __builtin_nontemporal_store(ob, (short4v*)&embb[(size_t)i * 512 + f]);
}

// ---- sliced propagate layer 2 (8 slices, 1 phase) ----
__global__ __launch_bounds__(256) void prop2_kernel(const u16t* __restrict__ T0,
    const u16t* __restrict__ colu, const i32x4* __restrict__ ndr,
    const u16t* __restrict__ perm, const float* __restrict__ b2,
    float* __restrict__ outp, int n, int Mrows) {
  const int t = threadIdx.x;
  const unsigned flb = (unsigned)(t & 7) * 8u;
  const int fl4 = (t & 7) * 4;
  const int bid = blockIdx.x;
  const int sl = bid & 7;
  const int slot = (bid >> 3) * 32 + (t >> 3);
  if (slot >= n) return;
  const int i = (int)perm[slot];

  const char* Tb = (const char*)T0 + (size_t)sl * ((size_t)Mrows * 64);
  const i32x4 nd = ndr[i];
  const float di = __int_as_float(nd[2]);
  f32x2 a01 = {0.f, 0.f}, a23 = {0.f, 0.f};

  int e = nd[0];
  const int end = nd[1];
  u32x4 cw = *(const u32x4*)&colu[e];
  e += 8;
  while (e < end) {
    u32x4 nw = *(const u32x4*)&colu[e];
    e += 8;
    gather8(Tb, cw, flb, a01, a23);
    cw = nw;
  }
  gather8(Tb, cw, flb, a01, a23);

  const int f = sl * 32 + fl4;
  float acc[4] = {a01.x, a01.y, a23.x, a23.y};
  f32x4 o;
#pragma unroll
  for (int j = 0; j < 4; ++j) o[j] = di * acc[j] + b2[f + j];
  __builtin_nontemporal_store(o, (f32x4*)&outp[(size_t)i * 256 + f]);
}

extern "C" void kernel_launch(void* const* d_in, const int* in_sizes, int n_in,
                              void* d_out, int out_size, void* d_ws, size_t ws_size,
                              hipStream_t stream) {
  (void)n_in; (void)out_size; (void)ws_size;
  const float* x  = (const float*)d_in[0];
  const int*   ei = (const int*)d_in[1];    // [2][E]: src row then dst row
  const float* W1 = (const float*)d_in[2];
  const float* b1 = (const float*)d_in[3];
  const float* W2 = (const float*)d_in[4];
  const float* b2 = (const float*)d_in[5];

  const int Nn = in_sizes[0] / 512;             // 50000
  const int E  = in_sizes[1] / 2;               // 800000
  const int Mpad = ((Nn + 127) / 128) * 128;    // 50048
  const int K = 512;
  const int CH = (Nn + 31) / 32;                // 32 nodes per slice-block

  char* ws = (char*)d_ws;
  size_t off = 0;
  auto take = [&](size_t bytes) -> char* {
    char* p = ws + off;
    off += (bytes + 255) & ~(size_t)255;
    return p;
  };
  u16t* xb   = (u16t*)take((size_t)Mpad * 512 * 2);      // x bf16; reused as emb bf16
  u16t* y1s  = (u16t*)take((size_t)16 * Mpad * 32 * 2);  // y1 slice-major; zs aliases
  u16t* W1b  = (u16t*)take((size_t)512 * 512 * 2);
  u16t* W2b  = (u16t*)take((size_t)256 * 512 * 2);
  // cnt[Nn] | gctr | hist[16] | binCursor[16]
  int*   cnt    = (int*)take((size_t)(Nn + 33) * 4);
  int*   cursor = (int*)take((size_t)Nn * 4);
  float* dinv   = (float*)take((size_t)Nn * 4);
  i32x4* ndr    = (i32x4*)take((size_t)Nn * 16);         // {start, end, dinv, 0}
  u16t*  perm   = (u16t*)take((size_t)Nn * 2);           // degree-binned node order
  u16t*  colu   = (u16t*)take((size_t)(E + 8 * (Nn + 1) + 64) * 2);  // padded CSR
  unsigned* kmask = (unsigned*)take((size_t)Nn * 16 * 4);  // slice-major keep bits

  float* embf = (float*)d_out;                       // [Nn,512]
  float* outf = (float*)d_out + (size_t)Nn * 512;    // [Nn,256]

  int* gctr      = cnt + Nn;
  int* hist      = cnt + Nn + 1;
  int* binCursor = cnt + Nn + 17;

  hipMemsetAsync(cnt, 0, (size_t)(Nn + 33) * 4, stream);

  const int n1 = Nn * 512;
  cvt_x_mask<<<(n1 / 4 + 255) / 256, 256, 0, stream>>>(x, xb, kmask, n1, Nn);
  cvt_bf16<<<(512 * 512 / 4 + 255) / 256, 256, 0, stream>>>(W1, W1b, 512 * 512);
  cvt_bf16<<<(256 * 512 / 4 + 255) / 256, 256, 0, stream>>>(W2, W2b, 256 * 512);

  count_edges<<<(E + 255) / 256, 256, 0, stream>>>(ei + E, E, cnt);
  bin_hist<<<(Nn + 255) / 256, 256, 0, stream>>>(cnt, hist, Nn);
  bin_scan<<<1, 64, 0, stream>>>(hist, binCursor);
  rowp_build<<<(Nn + 255) / 256, 256, 0, stream>>>(cnt, ndr, cursor, dinv, gctr,
                                                   colu, binCursor, perm, Nn);
  fill_csr<<<(E + 255) / 256, 256, 0, stream>>>(ei, ei + E, E, cursor, colu);

  // layer 1: y1 = dinv * (x @ W1^T), slice-major; then XCD-sliced propagate
  dim3 g1(Mpad / 128, 4);
  gemm_bt_sl<<<g1, 256, 0, stream>>>(xb, W1b, y1s, K, Mpad, dinv, Nn);
  prop1_kernel<<<16 * CH, 256, 0, stream>>>(y1s, colu, ndr, perm, b1, kmask,
                                            embf, xb /* emb bf16 */, Nn, Mpad, CH);

  // layer 2: z = dinv * (emb @ W2^T), slice-major; then propagate + b2
  u16t* zs = y1s;  // alias: y1 dead after prop1
  dim3 g2(Mpad / 128, 2);
  gemm_bt_sl<<<g2, 256, 0, stream>>>(xb, W2b, zs, K, Mpad, dinv, Nn);
  prop2_kernel<<<8 * CH, 256, 0, stream>>>(zs, colu, ndr, perm, b2, outf, Nn, Mpad);
}

// Round 6
// 588.803 us; speedup vs baseline: 2.2784x; 2.2784x over previous
//
#include <hip/hip_runtime.h>

typedef unsigned short u16t;
typedef __attribute__((ext_vector_type(8))) short short8;
typedef __attribute__((ext_vector_type(4))) short short4v;
typedef __attribute__((ext_vector_type(4))) float f32x4;
typedef __attribute__((ext_vector_type(2))) float f32x2;
typedef __attribute__((ext_vector_type(4))) unsigned short u16x4;
typedef __attribute__((ext_vector_type(4))) unsigned int u32x4;
typedef __attribute__((ext_vector_type(2))) unsigned int u32x2;
typedef __attribute__((ext_vector_type(4))) int i32x4;

__device__ __forceinline__ float bf2f(short b) {
  return __uint_as_float(((unsigned)(unsigned short)b) << 16);
}
__device__ __forceinline__ u16t f2bf(float f) {
  unsigned u = __float_as_uint(f);
  u += 0x7FFFu + ((u >> 16) & 1u);  // RNE
  return (u16t)(u >> 16);
}

// jax threefry2x32, key = (0, 42)
__device__ __forceinline__ bool keep_mask(unsigned flat) {
  const unsigned k0 = 0u, k1 = 42u;
  const unsigned k2 = k0 ^ k1 ^ 0x1BD11BDAu;
  unsigned x0 = 0u + k0;
  unsigned x1 = flat + k1;
#define TF_R(r) { x0 += x1; x1 = (x1 << r) | (x1 >> (32 - r)); x1 ^= x0; }
  TF_R(13) TF_R(15) TF_R(26) TF_R(6)  x0 += k1; x1 += k2 + 1u;
  TF_R(17) TF_R(29) TF_R(16) TF_R(24) x0 += k2; x1 += k0 + 2u;
  TF_R(13) TF_R(15) TF_R(26) TF_R(6)  x0 += k0; x1 += k1 + 3u;
  TF_R(17) TF_R(29) TF_R(16) TF_R(24) x0 += k1; x1 += k2 + 4u;
  TF_R(13) TF_R(15) TF_R(26) TF_R(6)  x0 += k2; x1 += k0 + 5u;
#undef TF_R
  return ((x0 ^ x1) >> 31) == 0u;
}

__device__ __forceinline__ void load_lds16(const u16t* g, u16t* l) {
  __builtin_amdgcn_global_load_lds((__attribute__((address_space(1))) void*)g,
                                   (__attribute__((address_space(3))) void*)l,
                                   16, 0, 0);
}

// ---- f32 -> bf16 conversion ----
__global__ void cvt_bf16(const float* __restrict__ s, u16t* __restrict__ d, int n) {
  int i = (blockIdx.x * 256 + threadIdx.x) * 4;
  if (i < n) {
    f32x4 v = *(const f32x4*)&s[i];
    u16x4 o = { f2bf(v.x), f2bf(v.y), f2bf(v.z), f2bf(v.w) };
    *(u16x4*)&d[i] = o;
  }
}

// ---- f32 -> bf16 for x, fused threefry mask precompute; mask is SLICE-MAJOR ----
__global__ __launch_bounds__(256) void cvt_x_mask(const float* __restrict__ s,
    u16t* __restrict__ d, unsigned* __restrict__ mask, int n, int nn) {
  int t = blockIdx.x * 256 + threadIdx.x;
  int i = t * 4;
  if (i < n) {
    f32x4 v = *(const f32x4*)&s[i];
    u16x4 o = { f2bf(v.x), f2bf(v.y), f2bf(v.z), f2bf(v.w) };
    *(u16x4*)&d[i] = o;
  }
  if (t < nn * 16) {
    unsigned base = (unsigned)t * 32u;
    unsigned m = 0u;
    for (int k = 0; k < 32; ++k) m |= (keep_mask(base + (unsigned)k) ? 1u : 0u) << k;
    mask[(size_t)(t & 15) * nn + (t >> 4)] = m;
  }
}

// ---- CSR build ----
__global__ void count_edges(const int* __restrict__ dst, int E, int* __restrict__ cnt) {
  int e = blockIdx.x * 256 + threadIdx.x;
  if (e < E) atomicAdd(&cnt[dst[e]], 1);
}

// Degree-bin histogram, LDS-aggregated: 16 global atomics per BLOCK, not per node.
__global__ __launch_bounds__(256) void bin_hist(const int* __restrict__ cnt,
                                                int* __restrict__ hist, int n) {
  __shared__ int sh[16];
  const int tid = threadIdx.x;
  if (tid < 16) sh[tid] = 0;
  __syncthreads();
  int i = blockIdx.x * 256 + tid;
  if (i < n) {
    int b = (cnt[i] + 8) >> 3;
    atomicAdd(&sh[b < 15 ? b : 15], 1);
  }
  __syncthreads();
  if (tid < 16 && sh[tid] > 0) atomicAdd(&hist[tid], sh[tid]);
}

__global__ void bin_scan(const int* __restrict__ hist, int* __restrict__ binCursor) {
  if (threadIdx.x == 0 && blockIdx.x == 0) {
    int s = 0;
    for (int b = 0; b < 16; ++b) { binCursor[b] = s; s += hist[b]; }
  }
}

// Padded CSR row build + degree-bin permutation, LDS-aggregated bin ranks:
// per-block LDS histogram gives each node its rank; one global atomic per
// (block, bin) reserves the block's span. Nodes in a wave share a bin AND a
// 256-id window -> divergence-free loops with decent read/write locality.
__global__ __launch_bounds__(256) void rowp_build(const int* __restrict__ cnt,
    i32x4* __restrict__ ndr, int* __restrict__ cursor, float* __restrict__ dinv,
    int* __restrict__ gctr, u16t* __restrict__ colu,
    int* __restrict__ binCursor, u16t* __restrict__ perm, int n) {
  __shared__ int sd[256];
  __shared__ int sbase;
  __shared__ int shist[16];
  __shared__ int sbinbase[16];
  const int tid = threadIdx.x;
  const int i = blockIdx.x * 256 + tid;
  int c = (i < n) ? cnt[i] : 0;
  int cs = c + 1;
  int p = (i < n) ? ((cs + 7) & ~7) : 0;
  int v = p;
  sd[tid] = v;
  if (tid < 16) shist[tid] = 0;
  __syncthreads();
  for (int o = 1; o < 256; o <<= 1) {
    int t2 = (tid >= o) ? sd[tid - o] : 0;
    __syncthreads();
    v += t2;
    sd[tid] = v;
    __syncthreads();
  }
  int b = p >> 3;
  b = b < 15 ? b : 15;
  int rank = 0;
  if (i < n) rank = atomicAdd(&shist[b], 1);
  if (tid == 255) sbase = atomicAdd(gctr, v);
  __syncthreads();
  if (tid < 16) sbinbase[tid] = (shist[tid] > 0) ? atomicAdd(&binCursor[tid], shist[tid]) : 0;
  __syncthreads();
  if (i < n) {
    int start = sbase + v - p;
    cursor[i] = start;
    float dv = rsqrtf((float)cs);
    dinv[i] = dv;
    i32x4 r;
    r[0] = start; r[1] = start + p; r[2] = __float_as_int(dv); r[3] = 0;
    ndr[i] = r;
    colu[start + c] = (u16t)i;                                  // self entry
    for (int q = c + 1; q < p; ++q) colu[start + q] = (u16t)n;  // dummies -> zero row
    perm[sbinbase[b] + rank] = (u16t)i;
  }
}

__global__ void fill_csr(const int* __restrict__ src, const int* __restrict__ dst, int E,
                         int* __restrict__ cursor, u16t* __restrict__ col) {
  int e = blockIdx.x * 256 + threadIdx.x;
  if (e < E) {
    int d = dst[e];
    int pos = atomicAdd(&cursor[d], 1);
    col[pos] = (u16t)src[e];
  }
}

// ---- bf16 GEMM, SLICE-MAJOR output, rows PRE-SCALED by dinv[row];
// rows >= Nclamp written as exact zeros (zero row for CSR dummies).
__global__ __launch_bounds__(256) void gemm_bt_sl(const u16t* __restrict__ A,
                                                  const u16t* __restrict__ B,
                                                  u16t* __restrict__ C,
                                                  int K, int Mrows,
                                                  const float* __restrict__ dinv,
                                                  int Nclamp) {
  __shared__ __align__(16) u16t lA[128 * 32];
  __shared__ __align__(16) u16t lB[128 * 32];
  const int tid = threadIdx.x;
  const int wave = tid >> 6, lane = tid & 63;
  const int wm = (wave & 1) * 64, wn = (wave >> 1) * 64;
  const int lrow = lane & 15, lq = lane >> 4;
  const u16t* Ab = A + (size_t)blockIdx.x * 128 * K;
  const u16t* Bb = B + (size_t)blockIdx.y * 128 * K;
  const int r0 = tid >> 2, c0 = (tid & 3) * 8;
  const int ldsOff = __builtin_amdgcn_readfirstlane((tid >> 6) * 512);

  f32x4 acc[4][4];
  const f32x4 zero = {0.f, 0.f, 0.f, 0.f};
#pragma unroll
  for (int mi = 0; mi < 4; ++mi)
#pragma unroll
    for (int ni = 0; ni < 4; ++ni) acc[mi][ni] = zero;

  for (int kt = 0; kt < K; kt += 32) {
    __syncthreads();
    load_lds16(Ab + (size_t)r0 * K + kt + c0, &lA[ldsOff]);
    load_lds16(Ab + (size_t)(r0 + 64) * K + kt + c0, &lA[2048 + ldsOff]);
    load_lds16(Bb + (size_t)r0 * K + kt + c0, &lB[ldsOff]);
    load_lds16(Bb + (size_t)(r0 + 64) * K + kt + c0, &lB[2048 + ldsOff]);
    __syncthreads();
    short8 af[4], bfr[4];
#pragma unroll
    for (int mi = 0; mi < 4; ++mi)
      af[mi] = *(const short8*)&lA[(wm + mi * 16 + lrow) * 32 + lq * 8];
#pragma unroll
    for (int ni = 0; ni < 4; ++ni)
      bfr[ni] = *(const short8*)&lB[(wn + ni * 16 + lrow) * 32 + lq * 8];
#pragma unroll
    for (int mi = 0; mi < 4; ++mi)
#pragma unroll
      for (int ni = 0; ni < 4; ++ni)
        acc[mi][ni] = __builtin_amdgcn_mfma_f32_16x16x32_bf16(af[mi], bfr[ni], acc[mi][ni], 0, 0, 0);
  }

  const int crow0 = blockIdx.x * 128 + wm + lq * 4;
  const int ccol0 = blockIdx.y * 128 + wn + lrow;
#pragma unroll
  for (int mi = 0; mi < 4; ++mi)
#pragma unroll
    for (int r = 0; r < 4; ++r) {
      const int row = crow0 + mi * 16 + r;
      const float dr = (row < Nclamp) ? dinv[row] : 0.f;
#pragma unroll
      for (int ni = 0; ni < 4; ++ni) {
        int cc = ccol0 + ni * 16;
        size_t idx = ((size_t)(cc >> 5) * Mrows + row) * 32 + (cc & 31);
        C[idx] = f2bf(dr * acc[mi][ni][r]);
      }
    }
}

// 8 edges: cols already in cw. Uniform SGPR base + 32-bit voffset (saddr-form
// global_load_dwordx2), shl/and bf16 unpack, f32x2 packed adds (v_pk_add_f32).
__device__ __forceinline__ void gather8(const char* __restrict__ Tb, u32x4 cw,
                                        unsigned flb, f32x2& a01, f32x2& a23) {
  unsigned off[8];
#pragma unroll
  for (int q = 0; q < 4; ++q) {
    off[2 * q]     = ((cw[q] & 0xFFFFu) << 6) | flb;
    off[2 * q + 1] = ((cw[q] >> 16) << 6) | flb;
  }
  u32x2 w[8];
#pragma unroll
  for (int q = 0; q < 8; ++q) w[q] = *(const u32x2*)(Tb + (size_t)off[q]);
#pragma unroll
  for (int q = 0; q < 8; ++q) {
    f32x2 v01 = { __uint_as_float(w[q].x << 16), __uint_as_float(w[q].x & 0xFFFF0000u) };
    f32x2 v23 = { __uint_as_float(w[q].y << 16), __uint_as_float(w[q].y & 0xFFFF0000u) };
    a01 += v01;
    a23 += v23;
  }
}

// ---- sliced propagate layer 1: 8 lanes/node, 32 nodes/block, degree-binned
// node order (perm) -> divergence-free chunk loops; padded CSR (no tails).
__global__ __launch_bounds__(256) void prop1_kernel(const u16t* __restrict__ T0,
    const u16t* __restrict__ colu, const i32x4* __restrict__ ndr,
    const u16t* __restrict__ perm, const float* __restrict__ b1,
    const unsigned* __restrict__ kmask,
    float* __restrict__ embf, u16t* __restrict__ embb, int n, int Mrows, int chunks) {
  const int t = threadIdx.x;
  const unsigned flb = (unsigned)(t & 7) * 8u;  // byte offset of lane's 4 feats
  const int fl4 = (t & 7) * 4;
  const int bid = blockIdx.x;
  const int half = chunks << 3;
  const int phase = bid >= half;
  const int rem = bid - (phase ? half : 0);
  const int sl = (rem & 7) + (phase << 3);
  const int slot = (rem >> 3) * 32 + (t >> 3);
  if (slot >= n) return;
  const int i = (int)perm[slot];

  const char* Tb = (const char*)T0 + (size_t)sl * ((size_t)Mrows * 64);
  const i32x4 nd = ndr[i];
  const float di = __int_as_float(nd[2]);
  f32x2 a01 = {0.f, 0.f}, a23 = {0.f, 0.f};

  int e = nd[0];
  const int end = nd[1];
  u32x4 cw = *(const u32x4*)&colu[e];
  e += 8;
  while (e < end) {
    u32x4 nw = *(const u32x4*)&colu[e];
    e += 8;
    gather8(Tb, cw, flb, a01, a23);
    cw = nw;
  }
  gather8(Tb, cw, flb, a01, a23);

  const int f = sl * 32 + fl4;
  const unsigned km = kmask[(size_t)sl * n + i];
  float acc[4] = {a01.x, a01.y, a23.x, a23.y};
  f32x4 o;
  short4v ob;
#pragma unroll
  for (int j = 0; j < 4; ++j) {
    float h = di * acc[j] + b1[f + j];
    h = fmaxf(h, 0.f);
    float eb = ((km >> (fl4 + j)) & 1u) ? 2.f * h : 0.f;
    o[j] = eb;
    ob[j] = (short)f2bf(eb);
  }
  __builtin_nontemporal_store(o, (f32x4*)&embf[(size_t)i * 512 + f]);
  __builtin_nontemporal_store(ob, (short4v*)&embb[(size_t)i * 512 + f]);
}

// ---- sliced propagate layer 2 (8 slices, 1 phase) ----
__global__ __launch_bounds__(256) void prop2_kernel(const u16t* __restrict__ T0,
    const u16t* __restrict__ colu, const i32x4* __restrict__ ndr,
    const u16t* __restrict__ perm, const float* __restrict__ b2,
    float* __restrict__ outp, int n, int Mrows) {
  const int t = threadIdx.x;
  const unsigned flb = (unsigned)(t & 7) * 8u;
  const int fl4 = (t & 7) * 4;
  const int bid = blockIdx.x;
  const int sl = bid & 7;
  const int slot = (bid >> 3) * 32 + (t >> 3);
  if (slot >= n) return;
  const int i = (int)perm[slot];

  const char* Tb = (const char*)T0 + (size_t)sl * ((size_t)Mrows * 64);
  const i32x4 nd = ndr[i];
  const float di = __int_as_float(nd[2]);
  f32x2 a01 = {0.f, 0.f}, a23 = {0.f, 0.f};

  int e = nd[0];
  const int end = nd[1];
  u32x4 cw = *(const u32x4*)&colu[e];
  e += 8;
  while (e < end) {
    u32x4 nw = *(const u32x4*)&colu[e];
    e += 8;
    gather8(Tb, cw, flb, a01, a23);
    cw = nw;
  }
  gather8(Tb, cw, flb, a01, a23);

  const int f = sl * 32 + fl4;
  float acc[4] = {a01.x, a01.y, a23.x, a23.y};
  f32x4 o;
#pragma unroll
  for (int j = 0; j < 4; ++j) o[j] = di * acc[j] + b2[f + j];
  __builtin_nontemporal_store(o, (f32x4*)&outp[(size_t)i * 256 + f]);
}

extern "C" void kernel_launch(void* const* d_in, const int* in_sizes, int n_in,
                              void* d_out, int out_size, void* d_ws, size_t ws_size,
                              hipStream_t stream) {
  (void)n_in; (void)out_size; (void)ws_size;
  const float* x  = (const float*)d_in[0];
  const int*   ei = (const int*)d_in[1];    // [2][E]: src row then dst row
  const float* W1 = (const float*)d_in[2];
  const float* b1 = (const float*)d_in[3];
  const float* W2 = (const float*)d_in[4];
  const float* b2 = (const float*)d_in[5];

  const int Nn = in_sizes[0] / 512;             // 50000
  const int E  = in_sizes[1] / 2;               // 800000
  const int Mpad = ((Nn + 127) / 128) * 128;    // 50048
  const int K = 512;
  const int CH = (Nn + 31) / 32;                // 32 nodes per slice-block

  char* ws = (char*)d_ws;
  size_t off = 0;
  auto take = [&](size_t bytes) -> char* {
    char* p = ws + off;
    off += (bytes + 255) & ~(size_t)255;
    return p;
  };
  u16t* xb   = (u16t*)take((size_t)Mpad * 512 * 2);      // x bf16; reused as emb bf16
  u16t* y1s  = (u16t*)take((size_t)16 * Mpad * 32 * 2);  // y1 slice-major; zs aliases
  u16t* W1b  = (u16t*)take((size_t)512 * 512 * 2);
  u16t* W2b  = (u16t*)take((size_t)256 * 512 * 2);
  // cnt[Nn] | gctr | hist[16] | binCursor[16]
  int*   cnt    = (int*)take((size_t)(Nn + 33) * 4);
  int*   cursor = (int*)take((size_t)Nn * 4);
  float* dinv   = (float*)take((size_t)Nn * 4);
  i32x4* ndr    = (i32x4*)take((size_t)Nn * 16);         // {start, end, dinv, 0}
  u16t*  perm   = (u16t*)take((size_t)Nn * 2);           // degree-binned node order
  u16t*  colu   = (u16t*)take((size_t)(E + 8 * (Nn + 1) + 64) * 2);  // padded CSR
  unsigned* kmask = (unsigned*)take((size_t)Nn * 16 * 4);  // slice-major keep bits

  float* embf = (float*)d_out;                       // [Nn,512]
  float* outf = (float*)d_out + (size_t)Nn * 512;    // [Nn,256]

  int* gctr      = cnt + Nn;
  int* hist      = cnt + Nn + 1;
  int* binCursor = cnt + Nn + 17;

  hipMemsetAsync(cnt, 0, (size_t)(Nn + 33) * 4, stream);

  const int n1 = Nn * 512;
  cvt_x_mask<<<(n1 / 4 + 255) / 256, 256, 0, stream>>>(x, xb, kmask, n1, Nn);
  cvt_bf16<<<(512 * 512 / 4 + 255) / 256, 256, 0, stream>>>(W1, W1b, 512 * 512);
  cvt_bf16<<<(256 * 512 / 4 + 255) / 256, 256, 0, stream>>>(W2, W2b, 256 * 512);

  count_edges<<<(E + 255) / 256, 256, 0, stream>>>(ei + E, E, cnt);
  bin_hist<<<(Nn + 255) / 256, 256, 0, stream>>>(cnt, hist, Nn);
  bin_scan<<<1, 64, 0, stream>>>(hist, binCursor);
  rowp_build<<<(Nn + 255) / 256, 256, 0, stream>>>(cnt, ndr, cursor, dinv, gctr,
                                                   colu, binCursor, perm, Nn);
  fill_csr<<<(E + 255) / 256, 256, 0, stream>>>(ei, ei + E, E, cursor, colu);

  // layer 1: y1 = dinv * (x @ W1^T), slice-major; then XCD-sliced propagate
  dim3 g1(Mpad / 128, 4);
  gemm_bt_sl<<<g1, 256, 0, stream>>>(xb, W1b, y1s, K, Mpad, dinv, Nn);
  prop1_kernel<<<16 * CH, 256, 0, stream>>>(y1s, colu, ndr, perm, b1, kmask,
                                            embf, xb /* emb bf16 */, Nn, Mpad, CH);

  // layer 2: z = dinv * (emb @ W2^T), slice-major; then propagate + b2
  u16t* zs = y1s;  // alias: y1 dead after prop1
  dim3 g2(Mpad / 128, 2);
  gemm_bt_sl<<<g2, 256, 0, stream>>>(xb, W2b, zs, K, Mpad, dinv, Nn);
  prop2_kernel<<<8 * CH, 256, 0, stream>>>(zs, colu, ndr, perm, b2, outf, Nn, Mpad);
}